// Round 1
// baseline (433.376 us; speedup 1.0000x reference)
//
#include <hip/hip_runtime.h>

typedef unsigned long long u64;
typedef unsigned int u32;

#define BB 8
#define LL 2048
#define MM 4096
#define KK 25
#define WPB 4            // waves (queries) per block
#define TPB 256

__device__ __forceinline__ u64 shfl_xor64(u64 v, int off) {
    u32 lo = (u32)v, hi = (u32)(v >> 32);
    lo = __shfl_xor(lo, off, 64);
    hi = __shfl_xor(hi, off, 64);
    return ((u64)hi << 32) | lo;
}

__global__ void __launch_bounds__(TPB) knn_kernel(
    const float* __restrict__ CB, const float* __restrict__ maskA,
    const float* __restrict__ Y, const int* __restrict__ Yt,
    const int* __restrict__ Ym, float* __restrict__ out)
{
    __shared__ float sX[MM];
    __shared__ float sYc[MM];
    __shared__ float sZ[MM];
    __shared__ u64 sM[MM / 64];

    const int tid  = threadIdx.x;
    const int lane = tid & 63;
    const int wv   = tid >> 6;
    const int blk  = blockIdx.x;
    const int b    = blk >> 9;        // 512 blocks per batch (LL/WPB)
    const int qg   = blk & 511;

    // ---- stage Y[b] coords into LDS planes (coalesced 12B/lane reads) ----
    const float* Yb = Y + (size_t)b * MM * 3;
    for (int p = tid; p < MM; p += TPB) {
        float x = Yb[3 * p + 0];
        float y = Yb[3 * p + 1];
        float z = Yb[3 * p + 2];
        sX[p] = x; sYc[p] = y; sZ[p] = z;
    }
    // ---- stage Y_m as bitmask: word w, bit i  <-> point p = w*64 + i ----
    const int* Ymb = Ym + (size_t)b * MM;
    for (int w = wv; w < MM / 64; w += WPB) {
        int p = (w << 6) | lane;
        u64 bal = __ballot(Ymb[p] != 0);
        if (lane == 0) sM[w] = bal;
    }
    __syncthreads();

    // ---- per-wave query ----
    const int l = (qg << 2) | wv;     // WPB = 4
    const int q = b * LL + l;
    const float cx = CB[3 * q + 0];
    const float cy = CB[3 * q + 1];
    const float cz = CB[3 * q + 2];
    const u64 mlAll = (maskA[q] != 0.0f) ? ~0ull : 0ull;

    // distances: exact numpy order ((dx*dx + dy*dy) + dz*dz), no contraction
    float cache[64];
#pragma unroll
    for (int j = 0; j < 64; ++j) {
        const int p = (j << 6) | lane;
        float dx = cx - sX[p];
        float dy = cy - sYc[p];
        float dz = cz - sZ[p];
        float dsq = __fadd_rn(__fadd_rn(__fmul_rn(dx, dx), __fmul_rn(dy, dy)),
                              __fmul_rn(dz, dz));
        u64 w = sM[j] & mlAll;                 // broadcast LDS read
        cache[j] = ((w >> lane) & 1ull) ? dsq : 1000.0f;
    }

    // ---- 25 extractions of the global min key, filtered by > last ----
    // key = (f32bits(val)+1) << 32 | p  : monotone (val >= 0), unique,
    // ties by smallest index — matches jax.lax.top_k exactly.
    u64 last = 0;
    u64 mykey = 0;
#pragma unroll 1
    for (int it = 0; it < KK; ++it) {
        u64 best = ~0ull;
#pragma unroll
        for (int j = 0; j < 64; ++j) {
            const u32 p = (u32)((j << 6) | lane);
            const u64 key = ((u64)(__float_as_uint(cache[j]) + 1u) << 32) | p;
            if (key > last && key < best) best = key;
        }
#pragma unroll
        for (int off = 32; off > 0; off >>= 1) {
            u64 o = shfl_xor64(best, off);
            if (o < best) best = o;
        }
        last = best;
        if (lane == it) mykey = best;
    }

    // ---- outputs (flat concat, all as float32) ----
    float* out_y = out;                                   // [B,L,K,3]
    float* out_t = out + (size_t)BB * LL * KK * 3;        // [B,L,K]
    float* out_m = out_t + (size_t)BB * LL * KK;          // [B,L,K]
    float* out_d = out_m + (size_t)BB * LL * KK;          // [B,L]

    if (lane < KK) {
        const int p   = (int)(mykey & 0xFFFFFFFFull);
        const float v = __uint_as_float((u32)(mykey >> 32) - 1u);
        const size_t o = (size_t)q * KK + lane;
        out_y[3 * o + 0] = sX[p];
        out_y[3 * o + 1] = sYc[p];
        out_y[3 * o + 2] = sZ[p];
        out_t[o] = (float)Yt[(size_t)b * MM + p];
        out_m[o] = (float)((sM[p >> 6] >> (p & 63)) & 1ull);
        if (lane == 0) out_d[q] = sqrtf(v);
    }
}

extern "C" void kernel_launch(void* const* d_in, const int* in_sizes, int n_in,
                              void* d_out, int out_size, void* d_ws, size_t ws_size,
                              hipStream_t stream) {
    const float* CB   = (const float*)d_in[0];
    const float* mask = (const float*)d_in[1];
    const float* Y    = (const float*)d_in[2];
    const int*   Yt   = (const int*)d_in[3];
    const int*   Ym   = (const int*)d_in[4];
    float* out = (float*)d_out;

    dim3 grid(BB * LL / WPB);
    dim3 block(TPB);
    hipLaunchKernelGGL(knn_kernel, grid, block, 0, stream, CB, mask, Y, Yt, Ym, out);
}

// Round 2
// 247.423 us; speedup vs baseline: 1.7516x; 1.7516x over previous
//
#include <hip/hip_runtime.h>

typedef unsigned long long u64;
typedef unsigned int u32;

#define BB 8
#define LL 2048
#define MM 4096
#define KK 25
#define WPB 8            // waves (queries) per block
#define TPB 512
#define SENT 0xFFFFFFFFFFFFFFFFull

__device__ __forceinline__ u64 shfl_xor64(u64 v, int off) {
    u32 lo = (u32)v, hi = (u32)(v >> 32);
    lo = __shfl_xor(lo, off, 64);
    hi = __shfl_xor(hi, off, 64);
    return ((u64)hi << 32) | lo;
}

__global__ void __launch_bounds__(TPB, 4) knn_kernel(
    const float* __restrict__ CB, const float* __restrict__ maskA,
    const float* __restrict__ Y, const int* __restrict__ Yt,
    const int* __restrict__ Ym, float* __restrict__ out)
{
    __shared__ float sX[MM];
    __shared__ float sYc[MM];
    __shared__ float sZ[MM];
    __shared__ u64 sM[MM / 64];

    const int tid  = threadIdx.x;
    const int lane = tid & 63;
    const int wv   = tid >> 6;
    const int blk  = blockIdx.x;
    const int b    = blk >> 8;        // 256 blocks per batch (LL/WPB)
    const int qg   = blk & 255;

    // ---- stage Y[b] coords into LDS planes (coalesced 12B/thread) ----
    const float* Yb = Y + (size_t)b * MM * 3;
    for (int p = tid; p < MM; p += TPB) {
        sX[p]  = Yb[3 * p + 0];
        sYc[p] = Yb[3 * p + 1];
        sZ[p]  = Yb[3 * p + 2];
    }
    // ---- stage Y_m as bitmask: word w bit i <-> point p = w*64 + i ----
    const int* Ymb = Ym + (size_t)b * MM;
    for (int w = wv; w < MM / 64; w += WPB) {
        u64 bal = __ballot(Ymb[(w << 6) | lane] != 0);
        if (lane == 0) sM[w] = bal;
    }
    __syncthreads();

    // ---- per-wave query ----
    const int l = qg * WPB + wv;
    const int q = b * LL + l;
    const float cx = CB[3 * q + 0];
    const float cy = CB[3 * q + 1];
    const float cz = CB[3 * q + 2];
    const u64 ml = (maskA[q] != 0.0f) ? ~0ull : 0ull;

    // ---- fused distance + per-lane stable top-3 (ascending by (v, j)) ----
    float cache[64];
    float v1 = 3.0e38f, v2 = 3.0e38f, v3 = 3.0e38f;
    int   j1 = 0, j2 = 0, j3 = 0;
#pragma unroll
    for (int j = 0; j < 64; ++j) {
        const int p = (j << 6) | lane;
        float dx = cx - sX[p];
        float dy = cy - sYc[p];
        float dz = cz - sZ[p];
        float dsq = __fadd_rn(__fadd_rn(__fmul_rn(dx, dx), __fmul_rn(dy, dy)),
                              __fmul_rn(dz, dz));
        u64 w = sM[j] & ml;
        float v = ((w >> lane) & 1ull) ? dsq : 1000.0f;
        cache[j] = v;
        // stable insertion (strict < keeps earlier j ahead on ties)
        bool  c3 = v < v3;
        float iv = c3 ? v : v3;
        int   ij = c3 ? j : j3;
        bool  cB = iv < v2;
        float tv = v2;  v2 = cB ? iv : v2;  float nv3 = cB ? tv : iv;
        int   tj = j2;  j2 = cB ? ij : j2;  int   nj3 = cB ? tj : ij;
        v3 = nv3; j3 = nj3;
        bool  cA = v2 < v1;
        tv = v1; v1 = cA ? v2 : v1; v2 = cA ? tv : v2;
        tj = j1; j1 = cA ? j2 : j1; j2 = cA ? tj : j2;
    }

    // 64-bit keys: value bits (>=0, monotone) in hi word, global index p in lo.
    u64 k1 = ((u64)__float_as_uint(v1) << 32) | (u32)((j1 << 6) | lane);
    u64 k2 = ((u64)__float_as_uint(v2) << 32) | (u32)((j2 << 6) | lane);
    u64 k3 = ((u64)__float_as_uint(v3) << 32) | (u32)((j3 << 6) | lane);
    u64 hi = 0;            // last key popped from THIS lane
    u64 mykey = 0;

    // ---- 25 extractions: butterfly-min over per-lane list heads ----
#pragma unroll 1
    for (int it = 0; it < KK; ++it) {
        bool need = (k1 == SENT);
        if (__any(need)) {             // rare: a lane consumed all 3
            u64 found = SENT;
#pragma unroll
            for (int j = 0; j < 64; ++j) {
                u64 key = ((u64)__float_as_uint(cache[j]) << 32)
                        | (u32)((j << 6) | lane);
                if (key > hi && key < found) found = key;
            }
            if (need) k1 = found;
        }
        u64 best = k1;
#pragma unroll
        for (int off = 32; off; off >>= 1) {
            u64 o = shfl_xor64(best, off);
            if (o < best) best = o;
        }
        if (lane == it) mykey = best;
        bool won = (k1 == best);       // keys unique -> exactly one winner
        u64 old1 = k1;
        if (won) { hi = old1; k1 = k2; k2 = k3; k3 = SENT; }
    }

    // ---- outputs (flat concat, all as float32) ----
    float* out_y = out;                                   // [B,L,K,3]
    float* out_t = out + (size_t)BB * LL * KK * 3;        // [B,L,K]
    float* out_m = out_t + (size_t)BB * LL * KK;          // [B,L,K]
    float* out_d = out_m + (size_t)BB * LL * KK;          // [B,L]

    if (lane < KK) {
        const int p   = (int)(mykey & 0xFFFFFFFFull);
        const float v = __uint_as_float((u32)(mykey >> 32));
        const size_t o = (size_t)q * KK + lane;
        out_y[3 * o + 0] = sX[p];
        out_y[3 * o + 1] = sYc[p];
        out_y[3 * o + 2] = sZ[p];
        out_t[o] = (float)Yt[(size_t)b * MM + p];
        out_m[o] = (float)((sM[p >> 6] >> (p & 63)) & 1ull);
        if (lane == 0) out_d[q] = sqrtf(v);
    }
}

extern "C" void kernel_launch(void* const* d_in, const int* in_sizes, int n_in,
                              void* d_out, int out_size, void* d_ws, size_t ws_size,
                              hipStream_t stream) {
    const float* CB   = (const float*)d_in[0];
    const float* mask = (const float*)d_in[1];
    const float* Y    = (const float*)d_in[2];
    const int*   Yt   = (const int*)d_in[3];
    const int*   Ym   = (const int*)d_in[4];
    float* out = (float*)d_out;

    dim3 grid(BB * LL / WPB);
    dim3 block(TPB);
    hipLaunchKernelGGL(knn_kernel, grid, block, 0, stream, CB, mask, Y, Yt, Ym, out);
}

// Round 4
// 183.191 us; speedup vs baseline: 2.3657x; 1.3506x over previous
//
#include <hip/hip_runtime.h>

// Forbid FMA contraction EVERYWHERE: the fallback path recomputes distances
// and must be bit-identical to the main loop AND to numpy's unfused
// ((dx*dx + dy*dy) + dz*dz). HIP's __f*_rn are plain ops in the AMD headers,
// so the pragma is the only reliable contraction barrier.
#pragma clang fp contract(off)

typedef unsigned long long u64;
typedef unsigned int u32;

#define BB 8
#define LL 2048
#define MM 4096
#define KK 25
#define WPB 8            // waves (queries) per block
#define TPB 512
#define SENT 0xFFFFFFFFFFFFFFFFull

__device__ __forceinline__ u64 shfl_xor64(u64 v, int off) {
    u32 lo = (u32)v, hi = (u32)(v >> 32);
    lo = __shfl_xor(lo, off, 64);
    hi = __shfl_xor(hi, off, 64);
    return ((u64)hi << 32) | lo;
}

__global__ void __launch_bounds__(TPB, 4) knn_kernel(
    const float* __restrict__ CB, const float* __restrict__ maskA,
    const float* __restrict__ Y, const int* __restrict__ Yt,
    const int* __restrict__ Ym, float* __restrict__ out)
{
    __shared__ float sX[MM];
    __shared__ float sYc[MM];
    __shared__ float sZ[MM];
    __shared__ u64 sM[MM / 64];

    const int tid  = threadIdx.x;
    const int lane = tid & 63;
    const int wv   = tid >> 6;
    const int blk  = blockIdx.x;
    const int b    = blk >> 8;        // 256 blocks per batch (LL/WPB)
    const int qg   = blk & 255;

    // ---- stage Y[b] coords into LDS planes ----
    const float* Yb = Y + (size_t)b * MM * 3;
    for (int p = tid; p < MM; p += TPB) {
        sX[p]  = Yb[3 * p + 0];
        sYc[p] = Yb[3 * p + 1];
        sZ[p]  = Yb[3 * p + 2];
    }
    // ---- stage Y_m as bitmask: word w bit i <-> point p = w*64 + i ----
    const int* Ymb = Ym + (size_t)b * MM;
    for (int w = wv; w < MM / 64; w += WPB) {
        u64 bal = __ballot(Ymb[(w << 6) | lane] != 0);
        if (lane == 0) sM[w] = bal;
    }
    __syncthreads();

    // ---- per-wave query ----
    const int l = qg * WPB + wv;
    const int q = b * LL + l;
    const float cx = CB[3 * q + 0];
    const float cy = CB[3 * q + 1];
    const float cz = CB[3 * q + 2];
    const u64 ml = (maskA[q] != 0.0f) ? ~0ull : 0ull;

    // Single source of truth for the masked distance — used by BOTH the main
    // pass and the fallback rescan; contract(off) makes it bit-exact always.
    auto distv = [&](int j) -> float {
        const int p = (j << 6) | lane;
        float dx = cx - sX[p];
        float dy = cy - sYc[p];
        float dz = cz - sZ[p];
        float dsq = (dx * dx + dy * dy) + dz * dz;
        u64 w = sM[j] & ml;
        return ((w >> lane) & 1ull) ? dsq : 1000.0f;
    };

    // ---- fused distance + per-lane stable top-3 (ascending by (v, j)) ----
    float v1 = 3.0e38f, v2 = 3.0e38f, v3 = 3.0e38f;
    int   j1 = 0, j2 = 0, j3 = 0;
#pragma unroll
    for (int j = 0; j < 64; ++j) {
        float v = distv(j);
        // stable cascade insert (strict < keeps earlier j ahead on ties);
        // c1 => c2 => c3 since v1<=v2<=v3
        bool c1 = v < v1, c2 = v < v2, c3 = v < v3;
        float nv3 = c3 ? (c2 ? v2 : v) : v3;  int nj3 = c3 ? (c2 ? j2 : j) : j3;
        float nv2 = c2 ? (c1 ? v1 : v) : v2;  int nj2 = c2 ? (c1 ? j1 : j) : j2;
        float nv1 = c1 ? v : v1;              int nj1 = c1 ? j : j1;
        v1 = nv1; v2 = nv2; v3 = nv3; j1 = nj1; j2 = nj2; j3 = nj3;
    }

    // keys: (value_bits + 1) << 32 | p — monotone in (value, index), unique.
    u64 k1 = ((u64)(__float_as_uint(v1) + 1u) << 32) | (u32)((j1 << 6) | lane);
    u64 k2 = ((u64)(__float_as_uint(v2) + 1u) << 32) | (u32)((j2 << 6) | lane);
    u64 k3 = ((u64)(__float_as_uint(v3) + 1u) << 32) | (u32)((j3 << 6) | lane);
    u64 hi = 0;            // key of last element popped from THIS lane
    u64 mykey = 0;

    // ---- 25 extractions: butterfly-min over per-lane list heads ----
#pragma unroll 1
    for (int it = 0; it < KK; ++it) {
        bool need = (k1 == SENT);
        if (__any(need)) {             // rare: some lane consumed its 3
            u64 found = SENT;
#pragma unroll 8
            for (int j = 0; j < 64; ++j) {
                float v = distv(j);
                u64 key = ((u64)(__float_as_uint(v) + 1u) << 32)
                        | (u32)((j << 6) | lane);
                if (key > hi && key < found) found = key;
            }
            if (need) k1 = found;
        }
        u64 best = k1;
#pragma unroll
        for (int off = 32; off; off >>= 1) {
            u64 o = shfl_xor64(best, off);
            if (o < best) best = o;
        }
        if (lane == it) mykey = best;
        if (k1 == best) {              // unique keys -> exactly one winner
            hi = k1; k1 = k2; k2 = k3; k3 = SENT;
        }
    }

    // ---- outputs (flat concat, all as float32) ----
    float* out_y = out;                                   // [B,L,K,3]
    float* out_t = out + (size_t)BB * LL * KK * 3;        // [B,L,K]
    float* out_m = out_t + (size_t)BB * LL * KK;          // [B,L,K]
    float* out_d = out_m + (size_t)BB * LL * KK;          // [B,L]

    if (lane < KK) {
        const int p   = (int)(mykey & 0xFFFFFFFFull);
        const float v = __uint_as_float((u32)(mykey >> 32) - 1u);
        const size_t o = (size_t)q * KK + lane;
        out_y[3 * o + 0] = sX[p];
        out_y[3 * o + 1] = sYc[p];
        out_y[3 * o + 2] = sZ[p];
        out_t[o] = (float)Yt[(size_t)b * MM + p];
        out_m[o] = (float)((sM[p >> 6] >> (p & 63)) & 1ull);
        if (lane == 0) out_d[q] = sqrtf(v);
    }
}

extern "C" void kernel_launch(void* const* d_in, const int* in_sizes, int n_in,
                              void* d_out, int out_size, void* d_ws, size_t ws_size,
                              hipStream_t stream) {
    const float* CB   = (const float*)d_in[0];
    const float* mask = (const float*)d_in[1];
    const float* Y    = (const float*)d_in[2];
    const int*   Yt   = (const int*)d_in[3];
    const int*   Ym   = (const int*)d_in[4];
    float* out = (float*)d_out;

    dim3 grid(BB * LL / WPB);
    dim3 block(TPB);
    hipLaunchKernelGGL(knn_kernel, grid, block, 0, stream, CB, mask, Y, Yt, Ym, out);
}

// Round 5
// 146.965 us; speedup vs baseline: 2.9488x; 1.2465x over previous
//
#include <hip/hip_runtime.h>

// Forbid FMA contraction EVERYWHERE: the fallback path recomputes distances
// and must be bit-identical to the main loop AND to numpy's unfused
// ((dx*dx + dy*dy) + dz*dz).
#pragma clang fp contract(off)

typedef unsigned long long u64;
typedef unsigned int u32;
typedef unsigned char u8;

#define BB 8
#define LL 2048
#define MM 4096
#define KK 25
#define WPB 16           // waves (queries) per block
#define TPB 1024
#define SENT 0xFFFFFFFFFFFFFFFFull

__device__ __forceinline__ u64 shfl_xor64(u64 v, int off) {
    u32 lo = (u32)v, hi = (u32)(v >> 32);
    lo = __shfl_xor(lo, off, 64);
    hi = __shfl_xor(hi, off, 64);
    return ((u64)hi << 32) | lo;
}

// 2 blocks/CU * 16 waves = 32 waves/CU (hw cap). LDS 53KB*2 fits in 160KB.
// launch_bounds(1024,8) caps VGPR at 64 so 8 waves/SIMD stay resident.
__global__ void __launch_bounds__(TPB, 8) knn_kernel(
    const float* __restrict__ CB, const float* __restrict__ maskA,
    const float* __restrict__ Y, const int* __restrict__ Yt,
    const int* __restrict__ Ym, float* __restrict__ out)
{
    __shared__ float sX[MM];
    __shared__ float sYc[MM];
    __shared__ float sZ[MM];
    __shared__ u8    sMB[MM];

    const int tid  = threadIdx.x;
    const int lane = tid & 63;
    const int wv   = tid >> 6;
    const int blk  = blockIdx.x;
    const int b    = blk >> 7;        // 128 blocks per batch (LL/WPB)
    const int qg   = blk & 127;

    // ---- stage Y[b] coords + Y_m bytes into LDS ----
    const float* Yb  = Y  + (size_t)b * MM * 3;
    const int*   Ymb = Ym + (size_t)b * MM;
    for (int p = tid; p < MM; p += TPB) {
        sX[p]  = Yb[3 * p + 0];
        sYc[p] = Yb[3 * p + 1];
        sZ[p]  = Yb[3 * p + 2];
        sMB[p] = (u8)Ymb[p];
    }
    __syncthreads();

    // ---- per-wave query ----
    const int l = qg * WPB + wv;
    const int q = b * LL + l;

    float* out_y = out;                                   // [B,L,K,3]
    float* out_t = out + (size_t)BB * LL * KK * 3;        // [B,L,K]
    float* out_m = out_t + (size_t)BB * LL * KK;          // [B,L,K]
    float* out_d = out_m + (size_t)BB * LL * KK;          // [B,L]

    // ---- fast path: query masked out => all values exactly 1000.0,
    // top_k ties resolve to indices 0..24 (verified by rounds 2/4 absmax=0).
    if (maskA[q] == 0.0f) {
        if (lane < KK) {
            const int p = lane;
            const size_t o = (size_t)q * KK + lane;
            out_y[3 * o + 0] = sX[p];
            out_y[3 * o + 1] = sYc[p];
            out_y[3 * o + 2] = sZ[p];
            out_t[o] = (float)Yt[(size_t)b * MM + p];
            out_m[o] = (float)sMB[p];
            if (lane == 0) out_d[q] = sqrtf(1000.0f);
        }
        return;
    }

    const float cx = CB[3 * q + 0];
    const float cy = CB[3 * q + 1];
    const float cz = CB[3 * q + 2];

    // Single source of truth for the masked distance — main pass + fallback;
    // contract(off) keeps it bit-exact vs numpy everywhere.
    auto distv = [&](int j) -> float {
        const int p = (j << 6) | lane;
        float dx = cx - sX[p];
        float dy = cy - sYc[p];
        float dz = cz - sZ[p];
        float dsq = (dx * dx + dy * dy) + dz * dz;
        return sMB[p] ? dsq : 1000.0f;
    };

    // ---- fused distance + per-lane stable top-4 (ascending by (v, j)) ----
    float v1 = 3.0e38f, v2 = 3.0e38f, v3 = 3.0e38f, v4 = 3.0e38f;
    int   j1 = 0, j2 = 0, j3 = 0, j4 = 0;
#pragma unroll
    for (int j = 0; j < 64; ++j) {
        float v = distv(j);
        // stable cascade insert (strict < keeps earlier j ahead on ties);
        // c1 => c2 => c3 => c4 since v1<=v2<=v3<=v4
        bool c1 = v < v1, c2 = v < v2, c3 = v < v3, c4 = v < v4;
        float nv4 = c4 ? (c3 ? v3 : v) : v4;  int nj4 = c4 ? (c3 ? j3 : j) : j4;
        float nv3 = c3 ? (c2 ? v2 : v) : v3;  int nj3 = c3 ? (c2 ? j2 : j) : j3;
        float nv2 = c2 ? (c1 ? v1 : v) : v2;  int nj2 = c2 ? (c1 ? j1 : j) : j2;
        float nv1 = c1 ? v : v1;              int nj1 = c1 ? j : j1;
        v1 = nv1; v2 = nv2; v3 = nv3; v4 = nv4;
        j1 = nj1; j2 = nj2; j3 = nj3; j4 = nj4;
    }

    // keys: (value_bits + 1) << 32 | p — monotone in (value, index), unique.
    u64 k1 = ((u64)(__float_as_uint(v1) + 1u) << 32) | (u32)((j1 << 6) | lane);
    u64 k2 = ((u64)(__float_as_uint(v2) + 1u) << 32) | (u32)((j2 << 6) | lane);
    u64 k3 = ((u64)(__float_as_uint(v3) + 1u) << 32) | (u32)((j3 << 6) | lane);
    u64 k4 = ((u64)(__float_as_uint(v4) + 1u) << 32) | (u32)((j4 << 6) | lane);
    u64 hi = 0;            // key of last element popped from THIS lane
    u64 mykey = 0;

    // ---- 25 extractions: butterfly-min over per-lane list heads ----
#pragma unroll 1
    for (int it = 0; it < KK; ++it) {
        bool need = (k1 == SENT);
        if (__any(need)) {             // rare (~3.5%): a lane consumed its 4
            u64 found = SENT;
#pragma unroll 8
            for (int j = 0; j < 64; ++j) {
                float v = distv(j);
                u64 key = ((u64)(__float_as_uint(v) + 1u) << 32)
                        | (u32)((j << 6) | lane);
                if (key > hi && key < found) found = key;
            }
            if (need) k1 = found;
        }
        u64 best = k1;
#pragma unroll
        for (int off = 32; off; off >>= 1) {
            u64 o = shfl_xor64(best, off);
            if (o < best) best = o;
        }
        if (lane == it) mykey = best;
        if (k1 == best) {              // unique keys -> exactly one winner
            hi = k1; k1 = k2; k2 = k3; k3 = k4; k4 = SENT;
        }
    }

    // ---- outputs (flat concat, all as float32) ----
    if (lane < KK) {
        const int p   = (int)(mykey & 0xFFFFFFFFull);
        const float v = __uint_as_float((u32)(mykey >> 32) - 1u);
        const size_t o = (size_t)q * KK + lane;
        out_y[3 * o + 0] = sX[p];
        out_y[3 * o + 1] = sYc[p];
        out_y[3 * o + 2] = sZ[p];
        out_t[o] = (float)Yt[(size_t)b * MM + p];
        out_m[o] = (float)sMB[p];
        if (lane == 0) out_d[q] = sqrtf(v);
    }
}

extern "C" void kernel_launch(void* const* d_in, const int* in_sizes, int n_in,
                              void* d_out, int out_size, void* d_ws, size_t ws_size,
                              hipStream_t stream) {
    const float* CB   = (const float*)d_in[0];
    const float* mask = (const float*)d_in[1];
    const float* Y    = (const float*)d_in[2];
    const int*   Yt   = (const int*)d_in[3];
    const int*   Ym   = (const int*)d_in[4];
    float* out = (float*)d_out;

    dim3 grid(BB * LL / WPB);
    dim3 block(TPB);
    hipLaunchKernelGGL(knn_kernel, grid, block, 0, stream, CB, mask, Y, Yt, Ym, out);
}

// Round 8
// 134.456 us; speedup vs baseline: 3.2232x; 1.0930x over previous
//
#include <hip/hip_runtime.h>

// Forbid FMA contraction EVERYWHERE: the fallback path recomputes distances
// and must be bit-identical to the main loop AND to numpy's unfused
// ((dx*dx + dy*dy) + dz*dz).
#pragma clang fp contract(off)

typedef unsigned long long u64;
typedef unsigned int u32;
typedef unsigned char u8;

#define BB 8
#define LL 2048
#define MM 4096
#define KK 25
#define WPB 16           // waves (queries) per block
#define TPB 1024
#define SENT 0xFFFFFFFFFFFFFFFFull

// ROUND 8 = round-5 kernel (PASSED, 94.5us) with exactly ONE change:
// the 25-iteration extraction uses a 32-bit value butterfly + ballot winner
// resolution instead of the 64-bit key butterfly. Bisection step after the
// round-6/7 multi-change restructure failed twice.
__global__ void __launch_bounds__(TPB, 8) knn_kernel(
    const float* __restrict__ CB, const float* __restrict__ maskA,
    const float* __restrict__ Y, const int* __restrict__ Yt,
    const int* __restrict__ Ym, float* __restrict__ out)
{
    __shared__ float sX[MM];
    __shared__ float sYc[MM];
    __shared__ float sZ[MM];
    __shared__ u8    sMB[MM];

    const int tid  = threadIdx.x;
    const int lane = tid & 63;
    const int wv   = tid >> 6;
    const int blk  = blockIdx.x;
    const int b    = blk >> 7;        // 128 blocks per batch (LL/WPB)
    const int qg   = blk & 127;

    // ---- stage Y[b] coords + Y_m bytes into LDS ----
    const float* Yb  = Y  + (size_t)b * MM * 3;
    const int*   Ymb = Ym + (size_t)b * MM;
    for (int p = tid; p < MM; p += TPB) {
        sX[p]  = Yb[3 * p + 0];
        sYc[p] = Yb[3 * p + 1];
        sZ[p]  = Yb[3 * p + 2];
        sMB[p] = (u8)Ymb[p];
    }
    __syncthreads();

    // ---- per-wave query ----
    const int l = qg * WPB + wv;
    const int q = b * LL + l;

    float* out_y = out;                                   // [B,L,K,3]
    float* out_t = out + (size_t)BB * LL * KK * 3;        // [B,L,K]
    float* out_m = out_t + (size_t)BB * LL * KK;          // [B,L,K]
    float* out_d = out_m + (size_t)BB * LL * KK;          // [B,L]

    // ---- fast path: query masked out => every value exactly 1000.0,
    // top_k ties resolve to indices 0..24 (verified rounds 2/4/5, absmax=0).
    if (maskA[q] == 0.0f) {
        if (lane < KK) {
            const int p = lane;
            const size_t o = (size_t)q * KK + lane;
            out_y[3 * o + 0] = sX[p];
            out_y[3 * o + 1] = sYc[p];
            out_y[3 * o + 2] = sZ[p];
            out_t[o] = (float)Yt[(size_t)b * MM + p];
            out_m[o] = (float)sMB[p];
            if (lane == 0) out_d[q] = sqrtf(1000.0f);
        }
        return;
    }

    const float cx = CB[3 * q + 0];
    const float cy = CB[3 * q + 1];
    const float cz = CB[3 * q + 2];

    // Single source of truth for the masked distance — main pass + fallback;
    // contract(off) keeps it bit-exact vs numpy everywhere.
    auto distv = [&](int j) -> float {
        const int p = (j << 6) | lane;
        float dx = cx - sX[p];
        float dy = cy - sYc[p];
        float dz = cz - sZ[p];
        float dsq = (dx * dx + dy * dy) + dz * dz;
        return sMB[p] ? dsq : 1000.0f;
    };

    // ---- fused distance + per-lane stable top-4 (ascending by (v, j)) ----
    float v1 = 3.0e38f, v2 = 3.0e38f, v3 = 3.0e38f, v4 = 3.0e38f;
    int   j1 = 0, j2 = 0, j3 = 0, j4 = 0;
#pragma unroll
    for (int j = 0; j < 64; ++j) {
        float v = distv(j);
        // stable cascade insert (strict < keeps earlier j ahead on ties);
        // c1 => c2 => c3 => c4 since v1<=v2<=v3<=v4
        bool c1 = v < v1, c2 = v < v2, c3 = v < v3, c4 = v < v4;
        float nv4 = c4 ? (c3 ? v3 : v) : v4;  int nj4 = c4 ? (c3 ? j3 : j) : j4;
        float nv3 = c3 ? (c2 ? v2 : v) : v3;  int nj3 = c3 ? (c2 ? j2 : j) : j3;
        float nv2 = c2 ? (c1 ? v1 : v) : v2;  int nj2 = c2 ? (c1 ? j1 : j) : j2;
        float nv1 = c1 ? v : v1;              int nj1 = c1 ? j : j1;
        v1 = nv1; v2 = nv2; v3 = nv3; v4 = nv4;
        j1 = nj1; j2 = nj2; j3 = nj3; j4 = nj4;
    }

    // keys: (value_bits + 1) << 32 | p — monotone in (value, index), unique.
    u64 k1 = ((u64)(__float_as_uint(v1) + 1u) << 32) | (u32)((j1 << 6) | lane);
    u64 k2 = ((u64)(__float_as_uint(v2) + 1u) << 32) | (u32)((j2 << 6) | lane);
    u64 k3 = ((u64)(__float_as_uint(v3) + 1u) << 32) | (u32)((j3 << 6) | lane);
    u64 k4 = ((u64)(__float_as_uint(v4) + 1u) << 32) | (u32)((j4 << 6) | lane);
    u64 lastpop = 0;                 // key of last element popped from THIS lane
    u64 mykey = 0;

    // ---- 25 extractions: 32-bit value butterfly + ballot winner ----
#pragma unroll 1
    for (int it = 0; it < KK; ++it) {
        bool need = (k1 == SENT);
        if (__any(need)) {             // rare (~3.5%): a lane consumed its 4
            u64 found = SENT;
#pragma unroll 8
            for (int j = 0; j < 64; ++j) {
                float v = distv(j);
                u64 key = ((u64)(__float_as_uint(v) + 1u) << 32)
                        | (u32)((j << 6) | lane);
                if (key > lastpop && key < found) found = key;
            }
            if (need) k1 = found;
        }
        const u32 vh = (u32)(k1 >> 32);   // value bits (+1)
        const u32 vl = (u32)k1;           // global index p
        u32 bv = vh;
#pragma unroll
        for (int off = 32; off; off >>= 1) {
            u32 o = __shfl_xor(bv, off, 64);
            bv = (o < bv) ? o : bv;
        }
        u64 ball = __ballot(vh == bv);
        u32 bp;
        if (__popcll(ball) == 1) {        // wave-uniform; ~always taken
            int wl = __ffsll((unsigned long long)ball) - 1;
            bp = (u32)__shfl((int)vl, wl, 64);
        } else {                          // exact value tie: min index wins
            u32 cp = (vh == bv) ? vl : 0xFFFFFFFFu;
#pragma unroll
            for (int off = 32; off; off >>= 1) {
                u32 o = __shfl_xor(cp, off, 64);
                cp = (o < cp) ? o : cp;
            }
            bp = cp;
        }
        if (lane == it) mykey = ((u64)bv << 32) | bp;
        if (vh == bv && vl == bp) {       // unique keys -> exactly one winner
            lastpop = k1;
            k1 = k2; k2 = k3; k3 = k4; k4 = SENT;
        }
    }

    // ---- outputs (flat concat, all as float32) ----
    if (lane < KK) {
        const int p   = (int)(mykey & 0xFFFFFFFFull);
        const float v = __uint_as_float((u32)(mykey >> 32) - 1u);
        const size_t o = (size_t)q * KK + lane;
        out_y[3 * o + 0] = sX[p];
        out_y[3 * o + 1] = sYc[p];
        out_y[3 * o + 2] = sZ[p];
        out_t[o] = (float)Yt[(size_t)b * MM + p];
        out_m[o] = (float)sMB[p];
        if (lane == 0) out_d[q] = sqrtf(v);
    }
}

extern "C" void kernel_launch(void* const* d_in, const int* in_sizes, int n_in,
                              void* d_out, int out_size, void* d_ws, size_t ws_size,
                              hipStream_t stream) {
    const float* CB   = (const float*)d_in[0];
    const float* mask = (const float*)d_in[1];
    const float* Y    = (const float*)d_in[2];
    const int*   Yt   = (const int*)d_in[3];
    const int*   Ym   = (const int*)d_in[4];
    float* out = (float*)d_out;

    dim3 grid(BB * LL / WPB);
    dim3 block(TPB);
    hipLaunchKernelGGL(knn_kernel, grid, block, 0, stream, CB, mask, Y, Yt, Ym, out);
}

// Round 9
// 129.138 us; speedup vs baseline: 3.3559x; 1.0412x over previous
//
#include <hip/hip_runtime.h>

// Forbid FMA contraction EVERYWHERE: the fallback path recomputes distances
// and must be bit-identical to the main loop AND to numpy's unfused
// ((dx*dx + dy*dy) + dz*dz).
#pragma clang fp contract(off)

typedef unsigned long long u64;
typedef unsigned int u32;

#define BB 8
#define LL 2048
#define MM 4096
#define KK 25
#define WPB 16           // waves (queries) per block
#define TPB 1024
#define SENT 0xFFFFFFFFFFFFFFFFull

// Wave64 all-lanes min-reduce. xor1/xor2 via quad_perm DPP, xor4/xor8 via
// half-row/row mirrors (mirror pairing crosses the already-reduced halves, a
// valid reduction combiner), xor16 via ds_swizzle, xor32 via bpermute shfl.
static __device__ __forceinline__ u32 wave_min_u32(u32 x) {
    u32 t;
    t = (u32)__builtin_amdgcn_update_dpp(0, (int)x, 0xB1, 0xF, 0xF, true);  // quad_perm(1,0,3,2) = xor1
    x = t < x ? t : x;
    t = (u32)__builtin_amdgcn_update_dpp(0, (int)x, 0x4E, 0xF, 0xF, true);  // quad_perm(2,3,0,1) = xor2
    x = t < x ? t : x;
    t = (u32)__builtin_amdgcn_update_dpp(0, (int)x, 0x141, 0xF, 0xF, true); // row_half_mirror (pairs across quads)
    x = t < x ? t : x;
    t = (u32)__builtin_amdgcn_update_dpp(0, (int)x, 0x140, 0xF, 0xF, true); // row_mirror (pairs across 8-halves)
    x = t < x ? t : x;
    t = (u32)__builtin_amdgcn_ds_swizzle((int)x, 0x401F);                   // xor16 (within 32-lane group)
    x = t < x ? t : x;
    t = (u32)__shfl_xor((int)x, 32, 64);                                    // xor32 (wave-wide bpermute)
    x = t < x ? t : x;
    return x;
}

// ROUND 9 = round-8 kernel (PASSED, 81.5us, absmax 0) with the SAME value
// semantics (masked = exact 1000.0f, same keys, same extraction logic), plus:
//  (1) float4 LDS staging -> 1x ds_read_b128/j, immediate offsets
//  (2) DPP-based wave-min in the extraction reduce
__global__ void __launch_bounds__(TPB, 8) knn_kernel(
    const float* __restrict__ CB, const float* __restrict__ maskA,
    const float* __restrict__ Y, const int* __restrict__ Yt,
    const int* __restrict__ Ym, float* __restrict__ out)
{
    // {x, y, z, wmask} per candidate; wmask = 0.0f (valid) or 1000.0f (masked).
    __shared__ float4 sP[MM];   // 64 KiB -> 2 blocks/CU (wave-cap bound anyway)

    const int tid  = threadIdx.x;
    const int lane = tid & 63;
    const int wv   = tid >> 6;
    const int blk  = blockIdx.x;
    const int b    = blk >> 7;        // 128 blocks per batch (LL/WPB)
    const int qg   = blk & 127;

    // ---- stage Y[b] + Y_m into LDS ----
    const float* Yb  = Y  + (size_t)b * MM * 3;
    const int*   Ymb = Ym + (size_t)b * MM;
    for (int p = tid; p < MM; p += TPB) {
        float4 v;
        v.x = Yb[3 * p + 0];
        v.y = Yb[3 * p + 1];
        v.z = Yb[3 * p + 2];
        v.w = Ymb[p] ? 0.0f : 1000.0f;
        sP[p] = v;
    }
    __syncthreads();

    // ---- per-wave query ----
    const int l = qg * WPB + wv;
    const int q = b * LL + l;

    float* out_y = out;                                   // [B,L,K,3]
    float* out_t = out + (size_t)BB * LL * KK * 3;        // [B,L,K]
    float* out_m = out_t + (size_t)BB * LL * KK;          // [B,L,K]
    float* out_d = out_m + (size_t)BB * LL * KK;          // [B,L]

    // ---- fast path: query masked out => every value exactly 1000.0,
    // top_k ties resolve to indices 0..24 (verified rounds 2/4/5/8, absmax=0).
    if (maskA[q] == 0.0f) {
        if (lane < KK) {
            const int p = lane;
            float4 c = sP[p];
            const size_t o = (size_t)q * KK + lane;
            out_y[3 * o + 0] = c.x;
            out_y[3 * o + 1] = c.y;
            out_y[3 * o + 2] = c.z;
            out_t[o] = (float)Yt[(size_t)b * MM + p];
            out_m[o] = (c.w == 0.0f) ? 1.0f : 0.0f;
            if (lane == 0) out_d[q] = sqrtf(1000.0f);
        }
        return;
    }

    const float cx = CB[3 * q + 0];
    const float cy = CB[3 * q + 1];
    const float cz = CB[3 * q + 2];

    // Single source of truth for the masked distance — main pass + fallback;
    // contract(off) keeps it bit-exact vs numpy everywhere. Identical values
    // to rounds 4/5/8: masked candidates are exactly 1000.0f.
    auto distv = [&](int j) -> float {
        float4 c = sP[(j << 6) | lane];
        float dx = cx - c.x;
        float dy = cy - c.y;
        float dz = cz - c.z;
        float dsq = (dx * dx + dy * dy) + dz * dz;
        return (c.w != 0.0f) ? c.w : dsq;
    };

    // ---- fused distance + per-lane stable top-4 (ascending by (v, j)) ----
    float v1 = 3.0e38f, v2 = 3.0e38f, v3 = 3.0e38f, v4 = 3.0e38f;
    int   j1 = 0, j2 = 0, j3 = 0, j4 = 0;
#pragma unroll
    for (int j = 0; j < 64; ++j) {
        float v = distv(j);
        // stable cascade insert (strict < keeps earlier j ahead on ties);
        // c1 => c2 => c3 => c4 since v1<=v2<=v3<=v4
        bool c1 = v < v1, c2 = v < v2, c3 = v < v3, c4 = v < v4;
        float nv4 = c4 ? (c3 ? v3 : v) : v4;  int nj4 = c4 ? (c3 ? j3 : j) : j4;
        float nv3 = c3 ? (c2 ? v2 : v) : v3;  int nj3 = c3 ? (c2 ? j2 : j) : j3;
        float nv2 = c2 ? (c1 ? v1 : v) : v2;  int nj2 = c2 ? (c1 ? j1 : j) : j2;
        float nv1 = c1 ? v : v1;              int nj1 = c1 ? j : j1;
        v1 = nv1; v2 = nv2; v3 = nv3; v4 = nv4;
        j1 = nj1; j2 = nj2; j3 = nj3; j4 = nj4;
    }

    // keys: (value_bits + 1) << 32 | p — monotone in (value, index), unique.
    u64 k1 = ((u64)(__float_as_uint(v1) + 1u) << 32) | (u32)((j1 << 6) | lane);
    u64 k2 = ((u64)(__float_as_uint(v2) + 1u) << 32) | (u32)((j2 << 6) | lane);
    u64 k3 = ((u64)(__float_as_uint(v3) + 1u) << 32) | (u32)((j3 << 6) | lane);
    u64 k4 = ((u64)(__float_as_uint(v4) + 1u) << 32) | (u32)((j4 << 6) | lane);
    u64 lastpop = 0;                 // key of last element popped from THIS lane
    u64 mykey = 0;

    // ---- 25 extractions: DPP value min-reduce + ballot winner ----
#pragma unroll 1
    for (int it = 0; it < KK; ++it) {
        bool need = (k1 == SENT);
        if (__any(need)) {             // rare (~3.5%): a lane consumed its 4
            u64 found = SENT;
#pragma unroll 8
            for (int j = 0; j < 64; ++j) {
                float v = distv(j);
                u64 key = ((u64)(__float_as_uint(v) + 1u) << 32)
                        | (u32)((j << 6) | lane);
                if (key > lastpop && key < found) found = key;
            }
            if (need) k1 = found;
        }
        const u32 vh = (u32)(k1 >> 32);   // value bits (+1)
        const u32 vl = (u32)k1;           // global index p
        const u32 bv = wave_min_u32(vh);
        u64 ball = __ballot(vh == bv);
        u32 bp;
        if (__popcll(ball) == 1) {        // wave-uniform; ~always taken
            int wl = __ffsll((unsigned long long)ball) - 1;
            bp = (u32)__shfl((int)vl, wl, 64);
        } else {                          // exact value tie: min index wins
            u32 cp = (vh == bv) ? vl : 0xFFFFFFFFu;
#pragma unroll
            for (int off = 32; off; off >>= 1) {
                u32 o = __shfl_xor(cp, off, 64);
                cp = (o < cp) ? o : cp;
            }
            bp = cp;
        }
        if (lane == it) mykey = ((u64)bv << 32) | bp;
        if (vh == bv && vl == bp) {       // unique keys -> exactly one winner
            lastpop = k1;
            k1 = k2; k2 = k3; k3 = k4; k4 = SENT;
        }
    }

    // ---- outputs (flat concat, all as float32) ----
    if (lane < KK) {
        const int p   = (int)(mykey & 0xFFFFFFFFull);
        const float v = __uint_as_float((u32)(mykey >> 32) - 1u);
        float4 c = sP[p];
        const size_t o = (size_t)q * KK + lane;
        out_y[3 * o + 0] = c.x;
        out_y[3 * o + 1] = c.y;
        out_y[3 * o + 2] = c.z;
        out_t[o] = (float)Yt[(size_t)b * MM + p];
        out_m[o] = (c.w == 0.0f) ? 1.0f : 0.0f;
        if (lane == 0) out_d[q] = sqrtf(v);
    }
}

extern "C" void kernel_launch(void* const* d_in, const int* in_sizes, int n_in,
                              void* d_out, int out_size, void* d_ws, size_t ws_size,
                              hipStream_t stream) {
    const float* CB   = (const float*)d_in[0];
    const float* mask = (const float*)d_in[1];
    const float* Y    = (const float*)d_in[2];
    const int*   Yt   = (const int*)d_in[3];
    const int*   Ym   = (const int*)d_in[4];
    float* out = (float*)d_out;

    dim3 grid(BB * LL / WPB);
    dim3 block(TPB);
    hipLaunchKernelGGL(knn_kernel, grid, block, 0, stream, CB, mask, Y, Yt, Ym, out);
}